// Round 8
// baseline (461.199 us; speedup 1.0000x reference)
//
#include <hip/hip_runtime.h>

#define W 64
#define D 256
#define NH 8
#define GSTRIDE 512

typedef unsigned short u16;
typedef __attribute__((ext_vector_type(8))) short bf16x8;
typedef __attribute__((ext_vector_type(4))) float f32x4;

__device__ __forceinline__ u16 f2bf(float f) {
    union { float f; unsigned u; } v; v.f = f;
    unsigned r = v.u + 0x7fffu + ((v.u >> 16) & 1u);
    return (u16)(r >> 16);
}

// ---------------- LDS layout (bytes) ----------------
// xs   : [64][264] u16  x bf16 staging; aliased by attn_out each window      33792
// buf  : per-wave [16][136] u16 transposer (q -> k -> vT -> P, time-muxed)    4352 x 8
// bias : [8][128] f32 rel-pos-bias table (loaded once per block)              4096
// total 72704 -> 2 blocks/CU
#define XS_ROW 264
#define BUF_ROW 136
#define OFF_BUF 33792
#define OFF_BIAS 68608

__global__ __launch_bounds__(512, 4) void win_attn5(
    const float* __restrict__ x, const float* __restrict__ bqkv,
    const float* __restrict__ bproj, const float* __restrict__ relb,
    const u16* __restrict__ wqkvT, const u16* __restrict__ wprojT,
    float* __restrict__ out, int nwin)
{
    __shared__ __align__(16) char smem[72704];

    const int tid  = threadIdx.x;
    const int lane = tid & 63;
    const int h    = tid >> 6;      // wave index == head
    const int l15  = lane & 15;
    const int g    = lane >> 4;

    u16*   xs      = (u16*)smem;
    u16*   buf     = (u16*)(smem + OFF_BUF) + h * 16 * BUF_ROW;
    float* bias_ld = (float*)(smem + OFF_BIAS);

    const f32x4 z4 = {0.f, 0.f, 0.f, 0.f};
    const int w0 = blockIdx.x;

    // ---------- Prologue: bias table + first window staging ----------
    for (int i = tid; i < NH * 127; i += 512)
        bias_ld[(i / 127) * 128 + (i % 127)] = relb[i];

    float4 pre[8];
    {
        const float* xw = x + (size_t)w0 * (W * D);
        #pragma unroll
        for (int i = 0; i < 8; ++i)
            pre[i] = *(const float4*)(xw + i * 2048 + tid * 4);
    }
    #pragma unroll
    for (int i = 0; i < 8; ++i) {
        int e = i * 2048 + tid * 4;
        ushort4 b;
        b.x = f2bf(pre[i].x); b.y = f2bf(pre[i].y);
        b.z = f2bf(pre[i].z); b.w = f2bf(pre[i].w);
        *(ushort4*)(xs + (e >> 8) * XS_ROW + (e & 255)) = b;
    }
    __syncthreads();

    for (int w = w0; w < nwin; w += GSTRIDE) {
        // ---------- Phase 1: QKV for head h; fragments kept in registers ----------
        bf16x8 qf[4], kf[4], vf[2][2];

        #pragma unroll
        for (int mat = 0; mat < 3; ++mat) {
            f32x4 acc[2][4];
            #pragma unroll
            for (int ct = 0; ct < 2; ++ct)
                #pragma unroll
                for (int rt = 0; rt < 4; ++rt)
                    acc[ct][rt] = z4;

            const u16* bp0 = wqkvT + (size_t)(mat * 256 + h * 32 + l15) * 256;
            const u16* bp1 = bp0 + 16 * 256;
            __builtin_amdgcn_s_setprio(1);
            #pragma unroll
            for (int ks = 0; ks < 8; ++ks) {
                bf16x8 b0 = *(const bf16x8*)(bp0 + ks * 32 + g * 8);
                bf16x8 b1 = *(const bf16x8*)(bp1 + ks * 32 + g * 8);
                #pragma unroll
                for (int rt = 0; rt < 4; ++rt) {
                    bf16x8 a = *(const bf16x8*)(xs + (16 * rt + l15) * XS_ROW + ks * 32 + g * 8);
                    acc[0][rt] = __builtin_amdgcn_mfma_f32_16x16x32_bf16(a, b0, acc[0][rt], 0, 0, 0);
                    acc[1][rt] = __builtin_amdgcn_mfma_f32_16x16x32_bf16(a, b1, acc[1][rt], 0, 0, 0);
                }
            }
            __builtin_amdgcn_s_setprio(0);
            const float bias0 = bqkv[mat * 256 + h * 32 + l15];
            const float bias1 = bqkv[mat * 256 + h * 32 + 16 + l15];

            asm volatile("s_waitcnt lgkmcnt(0)" ::: "memory");   // WAR: prior buf reads done
            if (mat < 2) {
                #pragma unroll
                for (int ct = 0; ct < 2; ++ct) {
                    const float bias = ct ? bias1 : bias0;
                    #pragma unroll
                    for (int rt = 0; rt < 4; ++rt)
                        #pragma unroll
                        for (int r = 0; r < 4; ++r)
                            buf[(4 * g + r) * BUF_ROW + rt * 32 + ct * 16 + l15] =
                                f2bf(acc[ct][rt][r] + bias);
                }
                asm volatile("s_waitcnt lgkmcnt(0)" ::: "memory");
                #pragma unroll
                for (int rt = 0; rt < 4; ++rt) {
                    bf16x8 fr = *(const bf16x8*)(buf + l15 * BUF_ROW + rt * 32 + g * 8);
                    if (mat == 0) qf[rt] = fr; else kf[rt] = fr;
                }
            } else {
                #pragma unroll
                for (int cd = 0; cd < 2; ++cd) {
                    const float bias = cd ? bias1 : bias0;
                    #pragma unroll
                    for (int rt = 0; rt < 4; ++rt) {
                        ushort4 pk;
                        pk.x = f2bf(acc[cd][rt][0] + bias);
                        pk.y = f2bf(acc[cd][rt][1] + bias);
                        pk.z = f2bf(acc[cd][rt][2] + bias);
                        pk.w = f2bf(acc[cd][rt][3] + bias);
                        *(ushort4*)(buf + l15 * BUF_ROW + cd * 72 + 16 * rt + 4 * g) = pk;
                    }
                }
                asm volatile("s_waitcnt lgkmcnt(0)" ::: "memory");
                #pragma unroll
                for (int ks = 0; ks < 2; ++ks)
                    #pragma unroll
                    for (int cd = 0; cd < 2; ++cd)
                        vf[ks][cd] = *(const bf16x8*)(buf + l15 * BUF_ROW + cd * 72 + ks * 32 + g * 8);
            }
            asm volatile("s_waitcnt lgkmcnt(0)" ::: "memory");
        }

        // issue next window's x loads (registers only; latency hides under attn+proj)
        const bool hn = (w + GSTRIDE) < nwin;
        if (hn) {
            const float* xn = x + (size_t)(w + GSTRIDE) * (W * D);
            #pragma unroll
            for (int i = 0; i < 8; ++i)
                pre[i] = *(const float4*)(xn + i * 2048 + tid * 4);
        }
        __syncthreads();   // all xs reads done -> ao may alias xs

        // ---------- Phase 2: attention (wave-private; P via buf; bias via LDS) ----------
        const float* b2 = bias_ld + h * 128;
        const float scale = 0.17677669529663687f;   // 1/sqrt(32)
        u16* ao = xs;

        #pragma unroll
        for (int rt = 0; rt < 4; ++rt) {
            f32x4 s[4];
            #pragma unroll
            for (int ct = 0; ct < 4; ++ct)
                s[ct] = __builtin_amdgcn_mfma_f32_16x16x32_bf16(qf[rt], kf[ct], z4, 0, 0, 0);

            asm volatile("s_waitcnt lgkmcnt(0)" ::: "memory");   // WAR: prev rt's pf reads done
            float psum[4] = {0.f, 0.f, 0.f, 0.f};
            #pragma unroll
            for (int ct = 0; ct < 4; ++ct) {
                const int ktok = 16 * ct + l15;
                #pragma unroll
                for (int r = 0; r < 4; ++r) {
                    const int qtok = 16 * rt + 4 * g + r;
                    float sv = s[ct][r] * scale + b2[ktok - qtok + 63];
                    float ee = __expf(sv);
                    psum[r] += ee;
                    buf[(4 * g + r) * BUF_ROW + ct * 16 + l15] = f2bf(ee);
                }
            }
            float inv[4];
            #pragma unroll
            for (int r = 0; r < 4; ++r) {
                float sum = psum[r];
                #pragma unroll
                for (int m = 1; m <= 8; m <<= 1)
                    sum += __shfl_xor(sum, m, 64);
                inv[r] = 1.0f / sum;
            }
            asm volatile("s_waitcnt lgkmcnt(0)" ::: "memory");
            bf16x8 pf0 = *(const bf16x8*)(buf + l15 * BUF_ROW + g * 8);
            bf16x8 pf1 = *(const bf16x8*)(buf + l15 * BUF_ROW + 32 + g * 8);
            #pragma unroll
            for (int cd = 0; cd < 2; ++cd) {
                f32x4 o = __builtin_amdgcn_mfma_f32_16x16x32_bf16(pf0, vf[0][cd], z4, 0, 0, 0);
                o = __builtin_amdgcn_mfma_f32_16x16x32_bf16(pf1, vf[1][cd], o, 0, 0, 0);
                #pragma unroll
                for (int r = 0; r < 4; ++r)
                    ao[(16 * rt + 4 * g + r) * XS_ROW + h * 32 + cd * 16 + l15] = f2bf(o[r] * inv[r]);
            }
        }
        __syncthreads();   // ao complete (cross-wave input to proj)

        // ---------- Phase 3: output projection (wave h -> cols h*32..+31) ----------
        f32x4 pacc[2][4];
        #pragma unroll
        for (int ct = 0; ct < 2; ++ct)
            #pragma unroll
            for (int rt = 0; rt < 4; ++rt)
                pacc[ct][rt] = z4;

        const u16* pp0 = wprojT + (size_t)(h * 32 + l15) * 256;
        const u16* pp1 = pp0 + 16 * 256;
        __builtin_amdgcn_s_setprio(1);
        #pragma unroll
        for (int ks = 0; ks < 8; ++ks) {
            bf16x8 b0 = *(const bf16x8*)(pp0 + ks * 32 + g * 8);
            bf16x8 b1 = *(const bf16x8*)(pp1 + ks * 32 + g * 8);
            #pragma unroll
            for (int rt = 0; rt < 4; ++rt) {
                bf16x8 a = *(const bf16x8*)(ao + (16 * rt + l15) * XS_ROW + ks * 32 + g * 8);
                pacc[0][rt] = __builtin_amdgcn_mfma_f32_16x16x32_bf16(a, b0, pacc[0][rt], 0, 0, 0);
                pacc[1][rt] = __builtin_amdgcn_mfma_f32_16x16x32_bf16(a, b1, pacc[1][rt], 0, 0, 0);
            }
        }
        __builtin_amdgcn_s_setprio(0);

        float* outw = out + (size_t)w * (W * D);
        #pragma unroll
        for (int ct = 0; ct < 2; ++ct) {
            const int n = h * 32 + ct * 16 + l15;
            const float bp = bproj[n];
            #pragma unroll
            for (int rt = 0; rt < 4; ++rt)
                #pragma unroll
                for (int r = 0; r < 4; ++r)
                    outw[(16 * rt + 4 * g + r) * D + n] = pacc[ct][rt][r] + bp;
        }
        __syncthreads();   // all ao reads done -> xs writable for next window

        if (hn) {
            #pragma unroll
            for (int i = 0; i < 8; ++i) {
                int e = i * 2048 + tid * 4;
                ushort4 b;
                b.x = f2bf(pre[i].x); b.y = f2bf(pre[i].y);
                b.z = f2bf(pre[i].z); b.w = f2bf(pre[i].w);
                *(ushort4*)(xs + (e >> 8) * XS_ROW + (e & 255)) = b;
            }
            __syncthreads();   // xs ready for next window
        }
    }
}

// Transpose + bf16-convert the weight matrices into workspace (L2-resident).
__global__ void prep_weights(const float* __restrict__ wqkv, const float* __restrict__ wproj,
                             u16* __restrict__ wqkvT, u16* __restrict__ wprojT)
{
    int i = blockIdx.x * 256 + threadIdx.x;
    if (i < 768 * 256) {
        int n = i >> 8, kk = i & 255;
        wqkvT[i] = f2bf(wqkv[kk * 768 + n]);
    } else {
        int j = i - 768 * 256;
        int n = j >> 8, kk = j & 255;
        wprojT[j] = f2bf(wproj[kk * 256 + n]);
    }
}

extern "C" void kernel_launch(void* const* d_in, const int* in_sizes, int n_in,
                              void* d_out, int out_size, void* d_ws, size_t ws_size,
                              hipStream_t stream)
{
    const float* x     = (const float*)d_in[0];
    const float* wqkv  = (const float*)d_in[1];
    const float* bqkv  = (const float*)d_in[2];
    const float* wproj = (const float*)d_in[3];
    const float* bproj = (const float*)d_in[4];
    const float* relb  = (const float*)d_in[5];

    u16* wqkvT  = (u16*)d_ws;                 // 768*256 u16
    u16* wprojT = wqkvT + 768 * 256;          // 256*256 u16

    prep_weights<<<1024, 256, 0, stream>>>(wqkv, wproj, wqkvT, wprojT);

    const int nwin = in_sizes[0] / (W * D);   // 4096
    const int grid = nwin < GSTRIDE ? nwin : GSTRIDE;
    win_attn5<<<grid, 512, 0, stream>>>(x, bqkv, bproj, relb, wqkvT, wprojT,
                                        (float*)d_out, nwin);
}

// Round 9
// 373.398 us; speedup vs baseline: 1.2351x; 1.2351x over previous
//
#include <hip/hip_runtime.h>

#define W 64
#define D 256
#define NH 8

typedef unsigned short u16;
typedef __attribute__((ext_vector_type(8))) short bf16x8;
typedef __attribute__((ext_vector_type(4))) float f32x4;

__device__ __forceinline__ u16 f2bf(float f) {
    union { float f; unsigned u; } v; v.f = f;
    unsigned r = v.u + 0x7fffu + ((v.u >> 16) & 1u);
    return (u16)(r >> 16);
}

// ---------------- LDS layout (bytes) ----------------
// xs   : [64][264] u16  x bf16 staging; dead after QKV; aliased by attn_out 33792
// buf  : per-wave [16][136] u16 transposer (q -> k -> vT -> P, time-muxed)   4352 x 8
// bias : [8][128] f32 rel-pos bias table                                     4096
// total 72704 -> 2 blocks/CU
#define XS_ROW 264
#define BUF_ROW 136
#define OFF_BUF 33792
#define OFF_BIAS 68608

__global__ __launch_bounds__(512, 4) void win_attn6(
    const float* __restrict__ x, const float* __restrict__ bqkv,
    const float* __restrict__ bproj, const float* __restrict__ relb,
    const u16* __restrict__ wqkvT, const u16* __restrict__ wprojT,
    float* __restrict__ out)
{
    __shared__ __align__(16) char smem[72704];

    const int tid  = threadIdx.x;
    const int lane = tid & 63;
    const int h    = tid >> 6;      // wave index == head
    const int l15  = lane & 15;
    const int g    = lane >> 4;
    const int w    = blockIdx.x;

    u16*   xs      = (u16*)smem;
    u16*   buf     = (u16*)(smem + OFF_BUF) + h * 16 * BUF_ROW;
    float* bias_ld = (float*)(smem + OFF_BIAS);

    const f32x4 z4 = {0.f, 0.f, 0.f, 0.f};

    // ---------- Phase 0: stage x window -> LDS bf16; bias table -> LDS ----------
    for (int i = tid; i < NH * 127; i += 512)
        bias_ld[(i / 127) * 128 + (i % 127)] = relb[i];

    const float* xw = x + (size_t)w * (W * D);
    #pragma unroll
    for (int i = 0; i < 8; ++i) {
        int e = i * 2048 + tid * 4;
        int row = e >> 8, col = e & 255;
        float4 v = *(const float4*)(xw + e);
        ushort4 b;
        b.x = f2bf(v.x); b.y = f2bf(v.y); b.z = f2bf(v.z); b.w = f2bf(v.w);
        *(ushort4*)(xs + row * XS_ROW + col) = b;
    }
    __syncthreads();

    // ---------- Phase 1: QKV for head h; fragments kept in registers ----------
    bf16x8 qf[4], kf[4], vf[2][2];

    #pragma unroll
    for (int mat = 0; mat < 3; ++mat) {
        f32x4 acc[2][4];
        #pragma unroll
        for (int ct = 0; ct < 2; ++ct)
            #pragma unroll
            for (int rt = 0; rt < 4; ++rt)
                acc[ct][rt] = z4;

        const u16* bp0 = wqkvT + (size_t)(mat * 256 + h * 32 + l15) * 256;
        const u16* bp1 = bp0 + 16 * 256;
        __builtin_amdgcn_s_setprio(1);
        #pragma unroll
        for (int ks = 0; ks < 8; ++ks) {
            bf16x8 b0 = *(const bf16x8*)(bp0 + ks * 32 + g * 8);
            bf16x8 b1 = *(const bf16x8*)(bp1 + ks * 32 + g * 8);
            #pragma unroll
            for (int rt = 0; rt < 4; ++rt) {
                bf16x8 a = *(const bf16x8*)(xs + (16 * rt + l15) * XS_ROW + ks * 32 + g * 8);
                acc[0][rt] = __builtin_amdgcn_mfma_f32_16x16x32_bf16(a, b0, acc[0][rt], 0, 0, 0);
                acc[1][rt] = __builtin_amdgcn_mfma_f32_16x16x32_bf16(a, b1, acc[1][rt], 0, 0, 0);
            }
        }
        __builtin_amdgcn_s_setprio(0);
        const float bias0 = bqkv[mat * 256 + h * 32 + l15];
        const float bias1 = bqkv[mat * 256 + h * 32 + 16 + l15];

        if (mat < 2) {
            // C-layout (lane=d col, row=4g+r) -> A-frag layout via per-wave LDS
            #pragma unroll
            for (int ct = 0; ct < 2; ++ct) {
                const float bias = ct ? bias1 : bias0;
                #pragma unroll
                for (int rt = 0; rt < 4; ++rt)
                    #pragma unroll
                    for (int r = 0; r < 4; ++r)
                        buf[(4 * g + r) * BUF_ROW + rt * 32 + ct * 16 + l15] =
                            f2bf(acc[ct][rt][r] + bias);
            }
            #pragma unroll
            for (int rt = 0; rt < 4; ++rt) {
                bf16x8 fr = *(const bf16x8*)(buf + l15 * BUF_ROW + rt * 32 + g * 8);
                if (mat == 0) qf[rt] = fr; else kf[rt] = fr;
            }
        } else {
            // v transposed: buf[d_local l15][cd*72 + tok], packed b64 per (cd,rt)
            #pragma unroll
            for (int cd = 0; cd < 2; ++cd) {
                const float bias = cd ? bias1 : bias0;
                #pragma unroll
                for (int rt = 0; rt < 4; ++rt) {
                    ushort4 pk;
                    pk.x = f2bf(acc[cd][rt][0] + bias);
                    pk.y = f2bf(acc[cd][rt][1] + bias);
                    pk.z = f2bf(acc[cd][rt][2] + bias);
                    pk.w = f2bf(acc[cd][rt][3] + bias);
                    *(ushort4*)(buf + l15 * BUF_ROW + cd * 72 + 16 * rt + 4 * g) = pk;
                }
            }
            #pragma unroll
            for (int ks = 0; ks < 2; ++ks)
                #pragma unroll
                for (int cd = 0; cd < 2; ++cd)
                    vf[ks][cd] = *(const bf16x8*)(buf + l15 * BUF_ROW + cd * 72 + ks * 32 + g * 8);
        }
    }
    __syncthreads();   // all xs reads done -> ao may alias xs

    // ---------- Phase 2: attention (wave-private; P via buf; bias via LDS) ----------
    const float* b2 = bias_ld + h * 128;
    const float scale = 0.17677669529663687f;   // 1/sqrt(32)
    u16* ao = xs;

    #pragma unroll
    for (int rt = 0; rt < 4; ++rt) {
        f32x4 s[4];
        #pragma unroll
        for (int ct = 0; ct < 4; ++ct)
            s[ct] = __builtin_amdgcn_mfma_f32_16x16x32_bf16(qf[rt], kf[ct], z4, 0, 0, 0);

        float psum[4] = {0.f, 0.f, 0.f, 0.f};
        #pragma unroll
        for (int ct = 0; ct < 4; ++ct) {
            const int ktok = 16 * ct + l15;
            #pragma unroll
            for (int r = 0; r < 4; ++r) {
                const int qtok = 16 * rt + 4 * g + r;
                float sv = s[ct][r] * scale + b2[ktok - qtok + 63];
                float ee = __expf(sv);
                psum[r] += ee;
                buf[(4 * g + r) * BUF_ROW + ct * 16 + l15] = f2bf(ee);
            }
        }
        float inv[4];
        #pragma unroll
        for (int r = 0; r < 4; ++r) {
            float sum = psum[r];
            #pragma unroll
            for (int m = 1; m <= 8; m <<= 1)
                sum += __shfl_xor(sum, m, 64);
            inv[r] = 1.0f / sum;
        }
        bf16x8 pf0 = *(const bf16x8*)(buf + l15 * BUF_ROW + g * 8);
        bf16x8 pf1 = *(const bf16x8*)(buf + l15 * BUF_ROW + 32 + g * 8);
        #pragma unroll
        for (int cd = 0; cd < 2; ++cd) {
            f32x4 o = __builtin_amdgcn_mfma_f32_16x16x32_bf16(pf0, vf[0][cd], z4, 0, 0, 0);
            o = __builtin_amdgcn_mfma_f32_16x16x32_bf16(pf1, vf[1][cd], o, 0, 0, 0);
            #pragma unroll
            for (int r = 0; r < 4; ++r)
                ao[(16 * rt + 4 * g + r) * XS_ROW + h * 32 + cd * 16 + l15] = f2bf(o[r] * inv[r]);
        }
    }
    __syncthreads();   // ao complete (cross-wave input to proj)

    // ---------- Phase 3: output projection (wave h -> cols h*32..+31) ----------
    f32x4 pacc[2][4];
    #pragma unroll
    for (int ct = 0; ct < 2; ++ct)
        #pragma unroll
        for (int rt = 0; rt < 4; ++rt)
            pacc[ct][rt] = z4;

    const u16* pp0 = wprojT + (size_t)(h * 32 + l15) * 256;
    const u16* pp1 = pp0 + 16 * 256;
    __builtin_amdgcn_s_setprio(1);
    #pragma unroll
    for (int ks = 0; ks < 8; ++ks) {
        bf16x8 b0 = *(const bf16x8*)(pp0 + ks * 32 + g * 8);
        bf16x8 b1 = *(const bf16x8*)(pp1 + ks * 32 + g * 8);
        #pragma unroll
        for (int rt = 0; rt < 4; ++rt) {
            bf16x8 a = *(const bf16x8*)(ao + (16 * rt + l15) * XS_ROW + ks * 32 + g * 8);
            pacc[0][rt] = __builtin_amdgcn_mfma_f32_16x16x32_bf16(a, b0, pacc[0][rt], 0, 0, 0);
            pacc[1][rt] = __builtin_amdgcn_mfma_f32_16x16x32_bf16(a, b1, pacc[1][rt], 0, 0, 0);
        }
    }
    __builtin_amdgcn_s_setprio(0);

    float* outw = out + (size_t)w * (W * D);
    #pragma unroll
    for (int ct = 0; ct < 2; ++ct) {
        const int n = h * 32 + ct * 16 + l15;
        const float bp = bproj[n];
        #pragma unroll
        for (int rt = 0; rt < 4; ++rt)
            #pragma unroll
            for (int r = 0; r < 4; ++r)
                outw[(16 * rt + 4 * g + r) * D + n] = pacc[ct][rt][r] + bp;
    }
}

// Transpose + bf16-convert the weight matrices into workspace (L2-resident).
__global__ void prep_weights(const float* __restrict__ wqkv, const float* __restrict__ wproj,
                             u16* __restrict__ wqkvT, u16* __restrict__ wprojT)
{
    int i = blockIdx.x * 256 + threadIdx.x;
    if (i < 768 * 256) {
        int n = i >> 8, kk = i & 255;
        wqkvT[i] = f2bf(wqkv[kk * 768 + n]);
    } else {
        int j = i - 768 * 256;
        int n = j >> 8, kk = j & 255;
        wprojT[j] = f2bf(wproj[kk * 256 + n]);
    }
}

extern "C" void kernel_launch(void* const* d_in, const int* in_sizes, int n_in,
                              void* d_out, int out_size, void* d_ws, size_t ws_size,
                              hipStream_t stream)
{
    const float* x     = (const float*)d_in[0];
    const float* wqkv  = (const float*)d_in[1];
    const float* bqkv  = (const float*)d_in[2];
    const float* wproj = (const float*)d_in[3];
    const float* bproj = (const float*)d_in[4];
    const float* relb  = (const float*)d_in[5];

    u16* wqkvT  = (u16*)d_ws;                 // 768*256 u16
    u16* wprojT = wqkvT + 768 * 256;          // 256*256 u16

    prep_weights<<<1024, 256, 0, stream>>>(wqkv, wproj, wqkvT, wprojT);

    const int nwin = in_sizes[0] / (W * D);   // 4096
    win_attn6<<<nwin, 512, 0, stream>>>(x, bqkv, bproj, relb, wqkvT, wprojT, (float*)d_out);
}

// Round 10
// 332.671 us; speedup vs baseline: 1.3864x; 1.1224x over previous
//
#include <hip/hip_runtime.h>

#define W 64
#define D 256
#define NH 8

typedef unsigned short u16;
typedef __attribute__((ext_vector_type(8))) short bf16x8;
typedef __attribute__((ext_vector_type(4))) float f32x4;

__device__ __forceinline__ u16 f2bf(float f) {
    union { float f; unsigned u; } v; v.f = f;
    unsigned r = v.u + 0x7fffu + ((v.u >> 16) & 1u);
    return (u16)(r >> 16);
}

// ---------------- LDS layout (bytes) ----------------
// xs  : [64][264] u16   x bf16 staging; dead after QKV; aliased by attn_out  33792
// buf : per-wave [16][72] u16 transposer (q/k 2-pass, v 2-pass, P)            2304 x 8
// total 52224 -> 3 blocks/CU IF unified regs/wave <= ~85 (launch_bounds must
// NOT squeeze the allocator: (512,4) gives the R5-proven no-spill allocation)
#define XS_ROW 264
#define BUF_ROW 72
#define OFF_BUF 33792

__global__ __launch_bounds__(512, 4) void win_attn7(
    const float* __restrict__ x, const float* __restrict__ bqkv,
    const float* __restrict__ bproj, const float* __restrict__ relb,
    const u16* __restrict__ wqkvT, const u16* __restrict__ wprojT,
    float* __restrict__ out)
{
    __shared__ __align__(16) char smem[52224];

    const int tid  = threadIdx.x;
    const int lane = tid & 63;
    const int h    = tid >> 6;      // wave index == head
    const int l15  = lane & 15;
    const int g    = lane >> 4;
    const int w    = blockIdx.x;

    u16* xs  = (u16*)smem;
    u16* buf = (u16*)(smem + OFF_BUF) + h * 16 * BUF_ROW;

    const f32x4 z4 = {0.f, 0.f, 0.f, 0.f};

    // ---------- Phase 0: stage x window -> LDS bf16 ----------
    const float* xw = x + (size_t)w * (W * D);
    #pragma unroll
    for (int i = 0; i < 8; ++i) {
        int e = i * 2048 + tid * 4;
        int row = e >> 8, col = e & 255;
        float4 v = *(const float4*)(xw + e);
        ushort4 b;
        b.x = f2bf(v.x); b.y = f2bf(v.y); b.z = f2bf(v.z); b.w = f2bf(v.w);
        *(ushort4*)(xs + row * XS_ROW + col) = b;
    }
    __syncthreads();

    // ---------- Phase 1: QKV for head h; fragments kept in registers ----------
    bf16x8 qf[4], kf[4], vf[2][2];

    #pragma unroll
    for (int mat = 0; mat < 3; ++mat) {
        f32x4 acc[2][4];
        #pragma unroll
        for (int ct = 0; ct < 2; ++ct)
            #pragma unroll
            for (int rt = 0; rt < 4; ++rt)
                acc[ct][rt] = z4;

        const u16* bp0 = wqkvT + (size_t)(mat * 256 + h * 32 + l15) * 256;
        const u16* bp1 = bp0 + 16 * 256;
        #pragma unroll
        for (int ks = 0; ks < 8; ++ks) {
            bf16x8 b0 = *(const bf16x8*)(bp0 + ks * 32 + g * 8);
            bf16x8 b1 = *(const bf16x8*)(bp1 + ks * 32 + g * 8);
            #pragma unroll
            for (int rt = 0; rt < 4; ++rt) {
                bf16x8 a = *(const bf16x8*)(xs + (16 * rt + l15) * XS_ROW + ks * 32 + g * 8);
                acc[0][rt] = __builtin_amdgcn_mfma_f32_16x16x32_bf16(a, b0, acc[0][rt], 0, 0, 0);
                acc[1][rt] = __builtin_amdgcn_mfma_f32_16x16x32_bf16(a, b1, acc[1][rt], 0, 0, 0);
            }
        }
        const float bias0 = bqkv[mat * 256 + h * 32 + l15];
        const float bias1 = bqkv[mat * 256 + h * 32 + 16 + l15];

        asm volatile("s_waitcnt lgkmcnt(0)" ::: "memory");   // WAR: prior buf reads done
        if (mat < 2) {
            // C-layout (lane=d col, row=4g+r) -> A-frag layout, 2 row-tiles per pass
            #pragma unroll
            for (int rp = 0; rp < 2; ++rp) {
                #pragma unroll
                for (int ct = 0; ct < 2; ++ct) {
                    const float bias = ct ? bias1 : bias0;
                    #pragma unroll
                    for (int rtl = 0; rtl < 2; ++rtl)
                        #pragma unroll
                        for (int r = 0; r < 4; ++r)
                            buf[(4 * g + r) * BUF_ROW + rtl * 32 + ct * 16 + l15] =
                                f2bf(acc[ct][2 * rp + rtl][r] + bias);
                }
                asm volatile("s_waitcnt lgkmcnt(0)" ::: "memory");
                #pragma unroll
                for (int rtl = 0; rtl < 2; ++rtl) {
                    bf16x8 fr = *(const bf16x8*)(buf + l15 * BUF_ROW + rtl * 32 + g * 8);
                    if (mat == 0) qf[2 * rp + rtl] = fr; else kf[2 * rp + rtl] = fr;
                }
                asm volatile("s_waitcnt lgkmcnt(0)" ::: "memory");   // WAR before next pass
            }
        } else {
            // v transposed: one cd (16 d-cols) per pass; token index packed b64
            #pragma unroll
            for (int cd = 0; cd < 2; ++cd) {
                const float bias = cd ? bias1 : bias0;
                #pragma unroll
                for (int rt = 0; rt < 4; ++rt) {
                    ushort4 pk;
                    pk.x = f2bf(acc[cd][rt][0] + bias);
                    pk.y = f2bf(acc[cd][rt][1] + bias);
                    pk.z = f2bf(acc[cd][rt][2] + bias);
                    pk.w = f2bf(acc[cd][rt][3] + bias);
                    *(ushort4*)(buf + l15 * BUF_ROW + 16 * rt + 4 * g) = pk;
                }
                asm volatile("s_waitcnt lgkmcnt(0)" ::: "memory");
                #pragma unroll
                for (int ks = 0; ks < 2; ++ks)
                    vf[ks][cd] = *(const bf16x8*)(buf + l15 * BUF_ROW + ks * 32 + g * 8);
                asm volatile("s_waitcnt lgkmcnt(0)" ::: "memory");   // WAR before next pass
            }
        }
    }
    __syncthreads();   // all xs reads done -> ao may alias xs

    // ---------- Phase 2: attention (wave-private; P via buf) ----------
    const float* b2 = relb + h * 127;
    const float scale = 0.17677669529663687f;   // 1/sqrt(32)
    u16* ao = xs;

    #pragma unroll
    for (int rt = 0; rt < 4; ++rt) {
        f32x4 s[4];
        #pragma unroll
        for (int ct = 0; ct < 4; ++ct)
            s[ct] = __builtin_amdgcn_mfma_f32_16x16x32_bf16(qf[rt], kf[ct], z4, 0, 0, 0);

        asm volatile("s_waitcnt lgkmcnt(0)" ::: "memory");   // WAR: prev rt's pf reads done
        float psum[4] = {0.f, 0.f, 0.f, 0.f};
        #pragma unroll
        for (int ct = 0; ct < 4; ++ct) {
            const int ktok = 16 * ct + l15;
            #pragma unroll
            for (int r = 0; r < 4; ++r) {
                const int qtok = 16 * rt + 4 * g + r;
                float sv = s[ct][r] * scale + b2[ktok - qtok + 63];
                float ee = __expf(sv);
                psum[r] += ee;
                buf[(4 * g + r) * BUF_ROW + ct * 16 + l15] = f2bf(ee);
            }
        }
        float inv[4];
        #pragma unroll
        for (int r = 0; r < 4; ++r) {
            float sum = psum[r];
            #pragma unroll
            for (int m = 1; m <= 8; m <<= 1)
                sum += __shfl_xor(sum, m, 64);
            inv[r] = 1.0f / sum;
        }
        asm volatile("s_waitcnt lgkmcnt(0)" ::: "memory");
        bf16x8 pf0 = *(const bf16x8*)(buf + l15 * BUF_ROW + g * 8);
        bf16x8 pf1 = *(const bf16x8*)(buf + l15 * BUF_ROW + 32 + g * 8);
        #pragma unroll
        for (int cd = 0; cd < 2; ++cd) {
            f32x4 o = __builtin_amdgcn_mfma_f32_16x16x32_bf16(pf0, vf[0][cd], z4, 0, 0, 0);
            o = __builtin_amdgcn_mfma_f32_16x16x32_bf16(pf1, vf[1][cd], o, 0, 0, 0);
            #pragma unroll
            for (int r = 0; r < 4; ++r)
                ao[(16 * rt + 4 * g + r) * XS_ROW + h * 32 + cd * 16 + l15] = f2bf(o[r] * inv[r]);
        }
    }
    __syncthreads();   // ao complete (cross-wave input to proj)

    // ---------- Phase 3: output projection (wave h -> cols h*32..+31) ----------
    f32x4 pacc[2][4];
    #pragma unroll
    for (int ct = 0; ct < 2; ++ct)
        #pragma unroll
        for (int rt = 0; rt < 4; ++rt)
            pacc[ct][rt] = z4;

    const u16* pp0 = wprojT + (size_t)(h * 32 + l15) * 256;
    const u16* pp1 = pp0 + 16 * 256;
    #pragma unroll
    for (int ks = 0; ks < 8; ++ks) {
        bf16x8 b0 = *(const bf16x8*)(pp0 + ks * 32 + g * 8);
        bf16x8 b1 = *(const bf16x8*)(pp1 + ks * 32 + g * 8);
        #pragma unroll
        for (int rt = 0; rt < 4; ++rt) {
            bf16x8 a = *(const bf16x8*)(ao + (16 * rt + l15) * XS_ROW + ks * 32 + g * 8);
            pacc[0][rt] = __builtin_amdgcn_mfma_f32_16x16x32_bf16(a, b0, pacc[0][rt], 0, 0, 0);
            pacc[1][rt] = __builtin_amdgcn_mfma_f32_16x16x32_bf16(a, b1, pacc[1][rt], 0, 0, 0);
        }
    }
    float* outw = out + (size_t)w * (W * D);
    #pragma unroll
    for (int ct = 0; ct < 2; ++ct) {
        const int n = h * 32 + ct * 16 + l15;
        const float bp = bproj[n];
        #pragma unroll
        for (int rt = 0; rt < 4; ++rt)
            #pragma unroll
            for (int r = 0; r < 4; ++r)
                outw[(16 * rt + 4 * g + r) * D + n] = pacc[ct][rt][r] + bp;
    }
}

// Transpose + bf16-convert the weight matrices into workspace (L2-resident).
__global__ void prep_weights(const float* __restrict__ wqkv, const float* __restrict__ wproj,
                             u16* __restrict__ wqkvT, u16* __restrict__ wprojT)
{
    int i = blockIdx.x * 256 + threadIdx.x;
    if (i < 768 * 256) {
        int n = i >> 8, kk = i & 255;
        wqkvT[i] = f2bf(wqkv[kk * 768 + n]);
    } else {
        int j = i - 768 * 256;
        int n = j >> 8, kk = j & 255;
        wprojT[j] = f2bf(wproj[kk * 256 + n]);
    }
}

extern "C" void kernel_launch(void* const* d_in, const int* in_sizes, int n_in,
                              void* d_out, int out_size, void* d_ws, size_t ws_size,
                              hipStream_t stream)
{
    const float* x     = (const float*)d_in[0];
    const float* wqkv  = (const float*)d_in[1];
    const float* bqkv  = (const float*)d_in[2];
    const float* wproj = (const float*)d_in[3];
    const float* bproj = (const float*)d_in[4];
    const float* relb  = (const float*)d_in[5];

    u16* wqkvT  = (u16*)d_ws;                 // 768*256 u16
    u16* wprojT = wqkvT + 768 * 256;          // 256*256 u16

    prep_weights<<<1024, 256, 0, stream>>>(wqkv, wproj, wqkvT, wprojT);

    const int nwin = in_sizes[0] / (W * D);   // 4096
    win_attn7<<<nwin, 512, 0, stream>>>(x, bqkv, bproj, relb, wqkvT, wprojT, (float*)d_out);
}